// Round 1
// baseline (234.234 us; speedup 1.0000x reference)
//
#include <hip/hip_runtime.h>

#define DD 64

// Node-level transform: A = (K_h + P_e) @ W1 + b1 ; B = Q_h @ W1
// One thread per node; W1/b1 accessed wave-uniformly -> scalar loads.
__global__ __launch_bounds__(256) void node_transform_kernel(
    const float* __restrict__ K_h, const float* __restrict__ Q_h,
    const float* __restrict__ P_e, const float* __restrict__ W1,
    const float* __restrict__ b1, float* __restrict__ A,
    float* __restrict__ Bm, int n_nodes)
{
    int n = blockIdx.x * blockDim.x + threadIdx.x;
    if (n >= n_nodes) return;

    float kp[DD];
    float q[DD];
    const float4* K4 = (const float4*)(K_h + (size_t)n * DD);
    const float4* Q4 = (const float4*)(Q_h + (size_t)n * DD);
    const float4* P4 = (const float4*)(P_e + (size_t)n * DD);
#pragma unroll
    for (int i = 0; i < DD / 4; ++i) {
        float4 k = K4[i];
        float4 p = P4[i];
        float4 qq = Q4[i];
        kp[4 * i + 0] = k.x + p.x;
        kp[4 * i + 1] = k.y + p.y;
        kp[4 * i + 2] = k.z + p.z;
        kp[4 * i + 3] = k.w + p.w;
        q[4 * i + 0] = qq.x;
        q[4 * i + 1] = qq.y;
        q[4 * i + 2] = qq.z;
        q[4 * i + 3] = qq.w;
    }

    float* Arow = A + (size_t)n * DD;
    float* Brow = Bm + (size_t)n * DD;
    for (int j = 0; j < DD; j += 4) {
        float4 accA = *(const float4*)(b1 + j);  // fold b1 into A
        float4 accB = make_float4(0.f, 0.f, 0.f, 0.f);
#pragma unroll
        for (int k = 0; k < DD; ++k) {
            float4 w = *(const float4*)(W1 + k * DD + j);  // uniform -> s_load
            accA.x = fmaf(kp[k], w.x, accA.x);
            accA.y = fmaf(kp[k], w.y, accA.y);
            accA.z = fmaf(kp[k], w.z, accA.z);
            accA.w = fmaf(kp[k], w.w, accA.w);
            accB.x = fmaf(q[k], w.x, accB.x);
            accB.y = fmaf(q[k], w.y, accB.y);
            accB.z = fmaf(q[k], w.z, accB.z);
            accB.w = fmaf(q[k], w.w, accB.w);
        }
        *(float4*)(Arow + j) = accA;
        *(float4*)(Brow + j) = accB;
    }
}

// Edge-level: score[e] = relu(A[src[e]] - B[dst[e]]) . W2 + b2
// One thread per edge; W2/b2 accessed wave-uniformly -> scalar loads.
__global__ __launch_bounds__(256) void edge_score_kernel(
    const float* __restrict__ A, const float* __restrict__ Bm,
    const int* __restrict__ src, const int* __restrict__ dst,
    const float* __restrict__ W2, const float* __restrict__ b2,
    float* __restrict__ out, int n_edges)
{
    int e = blockIdx.x * blockDim.x + threadIdx.x;
    if (e >= n_edges) return;

    const float4* Ar = (const float4*)(A + (size_t)src[e] * DD);
    const float4* Br = (const float4*)(Bm + (size_t)dst[e] * DD);

    float score = b2[0];
#pragma unroll
    for (int i = 0; i < DD / 4; ++i) {
        float4 a = Ar[i];
        float4 b = Br[i];
        float4 w = *(const float4*)(W2 + 4 * i);  // uniform -> s_load
        float h0 = fmaxf(a.x - b.x, 0.f);
        float h1 = fmaxf(a.y - b.y, 0.f);
        float h2 = fmaxf(a.z - b.z, 0.f);
        float h3 = fmaxf(a.w - b.w, 0.f);
        score = fmaf(h0, w.x, score);
        score = fmaf(h1, w.y, score);
        score = fmaf(h2, w.z, score);
        score = fmaf(h3, w.w, score);
    }
    out[e] = score;
}

extern "C" void kernel_launch(void* const* d_in, const int* in_sizes, int n_in,
                              void* d_out, int out_size, void* d_ws, size_t ws_size,
                              hipStream_t stream) {
    const float* K_h = (const float*)d_in[0];
    const float* Q_h = (const float*)d_in[1];
    const float* P_e = (const float*)d_in[2];
    const int*   src = (const int*)d_in[3];
    const int*   dst = (const int*)d_in[4];
    const float* W1  = (const float*)d_in[5];
    const float* b1  = (const float*)d_in[6];
    const float* W2  = (const float*)d_in[7];
    const float* b2  = (const float*)d_in[8];
    float* out = (float*)d_out;

    int n_nodes = in_sizes[0] / DD;
    int n_edges = in_sizes[3];

    // Workspace: A [n_nodes][64] fp32, B [n_nodes][64] fp32  (25.6 MB total)
    float* A  = (float*)d_ws;
    float* Bm = A + (size_t)n_nodes * DD;

    node_transform_kernel<<<(n_nodes + 255) / 256, 256, 0, stream>>>(
        K_h, Q_h, P_e, W1, b1, A, Bm, n_nodes);
    edge_score_kernel<<<(n_edges + 255) / 256, 256, 0, stream>>>(
        A, Bm, src, dst, W2, b2, out, n_edges);
}

// Round 2
// 153.647 us; speedup vs baseline: 1.5245x; 1.5245x over previous
//
#include <hip/hip_runtime.h>
#include <hip/hip_fp16.h>

#define DD 64
#define NPB 64          // nodes per block (node kernel)
#define LS 68           // padded LDS row stride (floats); 68*4=272 B keeps 16B alignment

// Node-level transform, GEMM-tiled:
//   A = (K_h + P_e) @ W1 + b1   (stored fp16)
//   B = Q_h @ W1                (stored fp16)
// Block: 256 threads, 64 nodes. Thread (ty,tx) computes 4 nodes x 4 cols for
// BOTH A and B. X staged transposed in LDS so the k-loop reads are b128.
__global__ __launch_bounds__(256) void node_transform_kernel(
    const float* __restrict__ K_h, const float* __restrict__ Q_h,
    const float* __restrict__ P_e, const float* __restrict__ W1,
    const float* __restrict__ b1, __half* __restrict__ A,
    __half* __restrict__ Bm, int n_nodes)
{
    __shared__ float kpT[DD][LS];  // [k][node_local]  (K+P, transposed)
    __shared__ float qT [DD][LS];  // [k][node_local]  (Q, transposed)
    __shared__ float ws [DD][DD];  // [k][c] — same layout as global W1

    const int tid   = threadIdx.x;
    const int nbase = blockIdx.x * NPB;

    // ---- Stage W1 straight copy (16 KB): 4 float4 per thread, coalesced ----
    {
        const float4* w4 = (const float4*)W1;
        float4* s4 = (float4*)&ws[0][0];
#pragma unroll
        for (int j = 0; j < 4; ++j) {
            int idx = tid + j * 256;   // 1024 float4 total
            s4[idx] = w4[idx];
        }
    }

    // ---- Stage X transposed: each thread loads 4 float4 per input array ----
#pragma unroll
    for (int j = 0; j < 4; ++j) {
        int chunk = tid + j * 256;        // float4 index over [64 nodes][16]
        int r  = chunk >> 4;              // node_local 0..63
        int k0 = (chunk & 15) << 2;       // 0,4,...,60
        int node = nbase + r;
        float4 kv = make_float4(0.f, 0.f, 0.f, 0.f);
        float4 pv = kv, qv = kv;
        if (node < n_nodes) {
            kv = *(const float4*)(K_h + (size_t)node * DD + k0);
            pv = *(const float4*)(P_e + (size_t)node * DD + k0);
            qv = *(const float4*)(Q_h + (size_t)node * DD + k0);
        }
        kpT[k0 + 0][r] = kv.x + pv.x;
        kpT[k0 + 1][r] = kv.y + pv.y;
        kpT[k0 + 2][r] = kv.z + pv.z;
        kpT[k0 + 3][r] = kv.w + pv.w;
        qT [k0 + 0][r] = qv.x;
        qT [k0 + 1][r] = qv.y;
        qT [k0 + 2][r] = qv.z;
        qT [k0 + 3][r] = qv.w;
    }
    __syncthreads();

    // ---- Main loop: 4x4 micro-tile, dual accumulators (A and B) ----
    const int tx = tid & 15;      // col group
    const int ty = tid >> 4;      // row group
    const int c0 = tx * 4;
    const int r0 = ty * 4;

    float4 bv = *(const float4*)(b1 + c0);   // fold b1 into A accumulator
    float accA[4][4], accB[4][4];
#pragma unroll
    for (int r = 0; r < 4; ++r) {
        accA[r][0] = bv.x; accA[r][1] = bv.y; accA[r][2] = bv.z; accA[r][3] = bv.w;
        accB[r][0] = 0.f;  accB[r][1] = 0.f;  accB[r][2] = 0.f;  accB[r][3] = 0.f;
    }

#pragma unroll 8
    for (int k = 0; k < DD; ++k) {
        float4 a4 = *(const float4*)&kpT[k][r0];   // 4 nodes' kp[k]
        float4 q4 = *(const float4*)&qT [k][r0];   // 4 nodes' q[k]
        float4 w4 = *(const float4*)&ws [k][c0];   // W1[k][c0..c0+3]
        const float av[4] = {a4.x, a4.y, a4.z, a4.w};
        const float qv[4] = {q4.x, q4.y, q4.z, q4.w};
        const float wv[4] = {w4.x, w4.y, w4.z, w4.w};
#pragma unroll
        for (int r = 0; r < 4; ++r) {
#pragma unroll
            for (int c = 0; c < 4; ++c) {
                accA[r][c] = fmaf(av[r], wv[c], accA[r][c]);
                accB[r][c] = fmaf(qv[r], wv[c], accB[r][c]);
            }
        }
    }

    // ---- Epilogue: convert to fp16, 8 B stores ----
#pragma unroll
    for (int r = 0; r < 4; ++r) {
        int node = nbase + r0 + r;
        if (node >= n_nodes) continue;
        union { __half2 h[2]; float2 f; } ua, ub;
        ua.h[0] = __float22half2_rn(make_float2(accA[r][0], accA[r][1]));
        ua.h[1] = __float22half2_rn(make_float2(accA[r][2], accA[r][3]));
        ub.h[0] = __float22half2_rn(make_float2(accB[r][0], accB[r][1]));
        ub.h[1] = __float22half2_rn(make_float2(accB[r][2], accB[r][3]));
        *(float2*)(A  + (size_t)node * DD + c0) = ua.f;
        *(float2*)(Bm + (size_t)node * DD + c0) = ub.f;
    }
}

// Edge-level: score[e] = relu(A[src[e]] - B[dst[e]]) . W2 + b2
// A/B are fp16 (128 B/row -> half the gather traffic of fp32).
__global__ __launch_bounds__(256) void edge_score_kernel(
    const __half* __restrict__ A, const __half* __restrict__ Bm,
    const int* __restrict__ src, const int* __restrict__ dst,
    const float* __restrict__ W2, const float* __restrict__ b2,
    float* __restrict__ out, int n_edges)
{
    int e = blockIdx.x * blockDim.x + threadIdx.x;
    if (e >= n_edges) return;

    const float4* Ar = (const float4*)(A  + (size_t)src[e] * DD);
    const float4* Br = (const float4*)(Bm + (size_t)dst[e] * DD);

    float score = b2[0];
#pragma unroll
    for (int i = 0; i < 8; ++i) {           // 8 chunks x 8 halves = 64
        float4 ar = Ar[i];
        float4 br = Br[i];
        const __half2* ah = (const __half2*)&ar;
        const __half2* bh = (const __half2*)&br;
        float4 w0 = *(const float4*)(W2 + i * 8);       // uniform -> s_load
        float4 w1 = *(const float4*)(W2 + i * 8 + 4);
        const float wv[8] = {w0.x, w0.y, w0.z, w0.w, w1.x, w1.y, w1.z, w1.w};
#pragma unroll
        for (int j = 0; j < 4; ++j) {
            float2 a2 = __half22float2(ah[j]);
            float2 b2v = __half22float2(bh[j]);
            score = fmaf(fmaxf(a2.x - b2v.x, 0.f), wv[2 * j + 0], score);
            score = fmaf(fmaxf(a2.y - b2v.y, 0.f), wv[2 * j + 1], score);
        }
    }
    out[e] = score;
}

extern "C" void kernel_launch(void* const* d_in, const int* in_sizes, int n_in,
                              void* d_out, int out_size, void* d_ws, size_t ws_size,
                              hipStream_t stream) {
    const float* K_h = (const float*)d_in[0];
    const float* Q_h = (const float*)d_in[1];
    const float* P_e = (const float*)d_in[2];
    const int*   src = (const int*)d_in[3];
    const int*   dst = (const int*)d_in[4];
    const float* W1  = (const float*)d_in[5];
    const float* b1  = (const float*)d_in[6];
    const float* W2  = (const float*)d_in[7];
    const float* b2  = (const float*)d_in[8];
    float* out = (float*)d_out;

    int n_nodes = in_sizes[0] / DD;
    int n_edges = in_sizes[3];

    // Workspace: A [n][64] fp16, B [n][64] fp16 (12.8 MB total)
    __half* A  = (__half*)d_ws;
    __half* Bm = A + (size_t)n_nodes * DD;

    node_transform_kernel<<<(n_nodes + NPB - 1) / NPB, 256, 0, stream>>>(
        K_h, Q_h, P_e, W1, b1, A, Bm, n_nodes);
    edge_score_kernel<<<(n_edges + 255) / 256, 256, 0, stream>>>(
        A, Bm, src, dst, W2, b2, out, n_edges);
}

// Round 3
// 133.778 us; speedup vs baseline: 1.7509x; 1.1485x over previous
//
#include <hip/hip_runtime.h>
#include <hip/hip_fp16.h>

#define DD 64
#define NPB 64          // nodes per block (node kernel)
#define LS 68           // padded LDS row stride (floats)

// Node-level transform, GEMM-tiled:
//   A = (K_h + P_e) @ W1 + b1   (stored fp16)
//   B = Q_h @ W1                (stored fp16)
__global__ __launch_bounds__(256) void node_transform_kernel(
    const float* __restrict__ K_h, const float* __restrict__ Q_h,
    const float* __restrict__ P_e, const float* __restrict__ W1,
    const float* __restrict__ b1, __half* __restrict__ A,
    __half* __restrict__ Bm, int n_nodes)
{
    __shared__ float kpT[DD][LS];  // [k][node_local]  (K+P, transposed)
    __shared__ float qT [DD][LS];  // [k][node_local]  (Q, transposed)
    __shared__ float ws [DD][DD];  // [k][c] — same layout as global W1

    const int tid   = threadIdx.x;
    const int nbase = blockIdx.x * NPB;

    // ---- Stage W1 straight copy (16 KB): coalesced float4 ----
    {
        const float4* w4 = (const float4*)W1;
        float4* s4 = (float4*)&ws[0][0];
#pragma unroll
        for (int j = 0; j < 4; ++j) {
            int idx = tid + j * 256;   // 1024 float4 total
            s4[idx] = w4[idx];
        }
    }

    // ---- Stage X transposed ----
#pragma unroll
    for (int j = 0; j < 4; ++j) {
        int chunk = tid + j * 256;        // float4 index over [64 nodes][16]
        int r  = chunk >> 4;              // node_local 0..63
        int k0 = (chunk & 15) << 2;       // 0,4,...,60
        int node = nbase + r;
        float4 kv = make_float4(0.f, 0.f, 0.f, 0.f);
        float4 pv = kv, qv = kv;
        if (node < n_nodes) {
            kv = *(const float4*)(K_h + (size_t)node * DD + k0);
            pv = *(const float4*)(P_e + (size_t)node * DD + k0);
            qv = *(const float4*)(Q_h + (size_t)node * DD + k0);
        }
        kpT[k0 + 0][r] = kv.x + pv.x;
        kpT[k0 + 1][r] = kv.y + pv.y;
        kpT[k0 + 2][r] = kv.z + pv.z;
        kpT[k0 + 3][r] = kv.w + pv.w;
        qT [k0 + 0][r] = qv.x;
        qT [k0 + 1][r] = qv.y;
        qT [k0 + 2][r] = qv.z;
        qT [k0 + 3][r] = qv.w;
    }
    __syncthreads();

    // ---- Main loop: 4x4 micro-tile, dual accumulators (A and B) ----
    const int tx = tid & 15;
    const int ty = tid >> 4;
    const int c0 = tx * 4;
    const int r0 = ty * 4;

    float4 bv = *(const float4*)(b1 + c0);   // fold b1 into A accumulator
    float accA[4][4], accB[4][4];
#pragma unroll
    for (int r = 0; r < 4; ++r) {
        accA[r][0] = bv.x; accA[r][1] = bv.y; accA[r][2] = bv.z; accA[r][3] = bv.w;
        accB[r][0] = 0.f;  accB[r][1] = 0.f;  accB[r][2] = 0.f;  accB[r][3] = 0.f;
    }

#pragma unroll 8
    for (int k = 0; k < DD; ++k) {
        float4 a4 = *(const float4*)&kpT[k][r0];
        float4 q4 = *(const float4*)&qT [k][r0];
        float4 w4 = *(const float4*)&ws [k][c0];
        const float av[4] = {a4.x, a4.y, a4.z, a4.w};
        const float qv[4] = {q4.x, q4.y, q4.z, q4.w};
        const float wv[4] = {w4.x, w4.y, w4.z, w4.w};
#pragma unroll
        for (int r = 0; r < 4; ++r) {
#pragma unroll
            for (int c = 0; c < 4; ++c) {
                accA[r][c] = fmaf(av[r], wv[c], accA[r][c]);
                accB[r][c] = fmaf(qv[r], wv[c], accB[r][c]);
            }
        }
    }

    // ---- Epilogue: convert to fp16, 8 B stores ----
#pragma unroll
    for (int r = 0; r < 4; ++r) {
        int node = nbase + r0 + r;
        if (node >= n_nodes) continue;
        union { __half2 h[2]; float2 f; } ua, ub;
        ua.h[0] = __float22half2_rn(make_float2(accA[r][0], accA[r][1]));
        ua.h[1] = __float22half2_rn(make_float2(accA[r][2], accA[r][3]));
        ub.h[0] = __float22half2_rn(make_float2(accB[r][0], accB[r][1]));
        ub.h[1] = __float22half2_rn(make_float2(accB[r][2], accB[r][3]));
        *(float2*)(A  + (size_t)node * DD + c0) = ua.f;
        *(float2*)(Bm + (size_t)node * DD + c0) = ub.f;
    }
}

// Edge-level: score[e] = relu(A[src[e]] - B[dst[e]]) . W2 + b2
// 8 lanes cooperate per edge: lane c loads the c-th 16B chunk of each fp16
// row, so every global_load_dwordx4 covers 8 complete contiguous 128-B rows
// (full L2-line utilization instead of 16B-per-transaction scatter).
__global__ __launch_bounds__(256) void edge_score_kernel(
    const __half* __restrict__ A, const __half* __restrict__ Bm,
    const int* __restrict__ src, const int* __restrict__ dst,
    const float* __restrict__ W2, const float* __restrict__ b2,
    float* __restrict__ out, int n_edges)
{
    const int tid = threadIdx.x;
    const int e = (blockIdx.x << 5) + (tid >> 3);  // 32 edges per 256-thr block
    const int c = tid & 7;                          // 16B chunk within row
    if (e >= n_edges) return;

    const int s = src[e];
    const int d = dst[e];

    float4 ar = *(const float4*)(A  + (size_t)s * DD + c * 8);
    float4 br = *(const float4*)(Bm + (size_t)d * DD + c * 8);
    float4 w0 = *(const float4*)(W2 + c * 8);
    float4 w1 = *(const float4*)(W2 + c * 8 + 4);

    const __half2* ah = (const __half2*)&ar;
    const __half2* bh = (const __half2*)&br;
    const float wv[8] = {w0.x, w0.y, w0.z, w0.w, w1.x, w1.y, w1.z, w1.w};

    float acc = 0.f;
#pragma unroll
    for (int j = 0; j < 4; ++j) {
        float2 a2  = __half22float2(ah[j]);
        float2 b2v = __half22float2(bh[j]);
        acc = fmaf(fmaxf(a2.x - b2v.x, 0.f), wv[2 * j + 0], acc);
        acc = fmaf(fmaxf(a2.y - b2v.y, 0.f), wv[2 * j + 1], acc);
    }

    // Reduce across the 8-lane group (xor masks stay within the group).
    acc += __shfl_xor(acc, 1);
    acc += __shfl_xor(acc, 2);
    acc += __shfl_xor(acc, 4);

    if (c == 0) out[e] = acc + b2[0];
}

extern "C" void kernel_launch(void* const* d_in, const int* in_sizes, int n_in,
                              void* d_out, int out_size, void* d_ws, size_t ws_size,
                              hipStream_t stream) {
    const float* K_h = (const float*)d_in[0];
    const float* Q_h = (const float*)d_in[1];
    const float* P_e = (const float*)d_in[2];
    const int*   src = (const int*)d_in[3];
    const int*   dst = (const int*)d_in[4];
    const float* W1  = (const float*)d_in[5];
    const float* b1  = (const float*)d_in[6];
    const float* W2  = (const float*)d_in[7];
    const float* b2  = (const float*)d_in[8];
    float* out = (float*)d_out;

    int n_nodes = in_sizes[0] / DD;
    int n_edges = in_sizes[3];

    // Workspace: A [n][64] fp16, B [n][64] fp16 (12.8 MB total)
    __half* A  = (__half*)d_ws;
    __half* Bm = A + (size_t)n_nodes * DD;

    node_transform_kernel<<<(n_nodes + NPB - 1) / NPB, 256, 0, stream>>>(
        K_h, Q_h, P_e, W1, b1, A, Bm, n_nodes);
    // 32 edges per block (8 lanes per edge)
    edge_score_kernel<<<(n_edges + 31) / 32, 256, 0, stream>>>(
        A, Bm, src, dst, W2, b2, out, n_edges);
}